// Round 13
// baseline (2124.086 us; speedup 1.0000x reference)
//
#include <hip/hip_runtime.h>
#include <hip/hip_bf16.h>

#define BATCH   131072
#define DIM     384
#define KC      256
#define NCB     4
#define ROWS    64
#define THREADS 512
#define NKT     12    // k-tiles of 32 (384 = 12*32)
#define NW      8     // waves per block
#define NBUF    8     // refine-row staging slots
#define AH_LD   392   // shorts per row for ahi/alo (784 B, 16B-aligned)
#define BUF_LD  388   // floats per row for refine buffer
#define MARGIN  2.5e-4f

typedef __attribute__((ext_vector_type(8))) short bf16x8;
typedef __attribute__((ext_vector_type(4))) float f32x4;

// numpy pairwise_sum, n=96 block of squares, 8 accumulators (order-preserving).
__device__ __forceinline__ float pw96_sq(const float* a) {
#pragma clang fp contract(off)
    float r0 = a[0]*a[0], r1 = a[1]*a[1], r2 = a[2]*a[2], r3 = a[3]*a[3];
    float r4 = a[4]*a[4], r5 = a[5]*a[5], r6 = a[6]*a[6], r7 = a[7]*a[7];
    for (int i = 8; i < 96; i += 8) {
        r0 += a[i+0]*a[i+0]; r1 += a[i+1]*a[i+1];
        r2 += a[i+2]*a[i+2]; r3 += a[i+3]*a[i+3];
        r4 += a[i+4]*a[i+4]; r5 += a[i+5]*a[i+5];
        r6 += a[i+6]*a[i+6]; r7 += a[i+7]*a[i+7];
    }
    return ((r0+r1)+(r2+r3))+((r4+r5)+(r6+r7));
}

// B_k = numpy pairwise sum of cb_k^2 over 384: ((P0+P1)+(P2+P3))
__global__ __launch_bounds__(256) void ccb_kernel(const float* __restrict__ cb,
                                                  float* __restrict__ bpw) {
    int i = blockIdx.x * 256 + threadIdx.x;
    if (i >= NCB * KC) return;
    const float* row = cb + (size_t)i * DIM;
    {
#pragma clang fp contract(off)
        float P0 = pw96_sq(row), P1 = pw96_sq(row + 96);
        float P2 = pw96_sq(row + 192), P3 = pw96_sq(row + 288);
        bpw[i] = (P0 + P1) + (P2 + P3);
    }
}

// Split codebook into k-tile-major bf16 hi/lo: out[((s*NKT+kt)*KC+cand)*32 + k]
__global__ __launch_bounds__(256) void split_kernel(const float* __restrict__ cb,
                                                    short* __restrict__ hi,
                                                    short* __restrict__ lo) {
    int idx = blockIdx.x * 256 + threadIdx.x;   // over 4*12*256*32 = 393216 elems
    if (idx >= NCB * NKT * KC * 32) return;
    int k    = idx & 31;
    int cand = (idx >> 5) & 255;
    int kt   = (idx >> 13) % NKT;
    int s    = idx / (NKT * KC * 32);
    float v = cb[((size_t)(s * KC + cand)) * DIM + kt * 32 + k];
    __hip_bfloat16 h = __float2bfloat16(v);
    float hv = __bfloat162float(h);
    __hip_bfloat16 l = __float2bfloat16(v - hv);
    hi[idx] = *reinterpret_cast<short*>(&h);
    lo[idx] = *reinterpret_cast<short*>(&l);
}

__device__ __forceinline__ void cvt4(float4 v, ushort4& h4, ushort4& l4) {
    float a0 = v.x, a1 = v.y, a2 = v.z, a3 = v.w;
    __hip_bfloat16 h0 = __float2bfloat16(a0), h1 = __float2bfloat16(a1);
    __hip_bfloat16 h2 = __float2bfloat16(a2), h3 = __float2bfloat16(a3);
    __hip_bfloat16 l0 = __float2bfloat16(a0 - __bfloat162float(h0));
    __hip_bfloat16 l1 = __float2bfloat16(a1 - __bfloat162float(h1));
    __hip_bfloat16 l2 = __float2bfloat16(a2 - __bfloat162float(h2));
    __hip_bfloat16 l3 = __float2bfloat16(a3 - __bfloat162float(h3));
    h4.x = *reinterpret_cast<unsigned short*>(&h0);
    h4.y = *reinterpret_cast<unsigned short*>(&h1);
    h4.z = *reinterpret_cast<unsigned short*>(&h2);
    h4.w = *reinterpret_cast<unsigned short*>(&h3);
    l4.x = *reinterpret_cast<unsigned short*>(&l0);
    l4.y = *reinterpret_cast<unsigned short*>(&l1);
    l4.z = *reinterpret_cast<unsigned short*>(&l2);
    l4.w = *reinterpret_cast<unsigned short*>(&l3);
}

__global__ __launch_bounds__(512) void rq_main(const float* __restrict__ x,
                                               const float* __restrict__ cb,
                                               float* __restrict__ out,
                                               const float* __restrict__ bpw,
                                               const short* __restrict__ cbh_g,
                                               const short* __restrict__ cbl_g,
                                               double* __restrict__ loss_part) {
    __shared__ short  ahi[ROWS][AH_LD];       // 50176 B
    __shared__ short  alo[ROWS][AH_LD];       // 50176 B
    __shared__ float  buf[NBUF][BUF_LD];      // 12416 B
    __shared__ float  rowbv[ROWS];            //   256 B
    __shared__ int    rowbk[ROWS];            //   256 B
    __shared__ int    rowslot[ROWS];          //   256 B
    __shared__ float  lvA[ROWS][NW];          //  2048 B
    __shared__ int    lkA[ROWS][NW];          //  2048 B
    __shared__ int    cntA[ROWS][NW];         //  2048 B
    __shared__ int    codes_s[ROWS][NCB];     //  1024 B
    __shared__ int    nref_s;                 //     4 B
    __shared__ double red[THREADS];           //  4096 B   => ~124.8 KB

    const int t  = threadIdx.x;
    const int w  = t >> 6;        // wave 0..7 (owns cand-tiles 2w, 2w+1)
    const int l  = t & 63;
    const int lg = l >> 4;        // k-group 0..3
    const int li = l & 15;
    const int row0 = blockIdx.x * ROWS;
    const float4* x4 = (const float4*)(x + (size_t)row0 * DIM);

    float4 rec[12];               // running reconstruction, this thread's 12 float4s
    #pragma unroll
    for (int i = 0; i < 12; ++i) rec[i] = make_float4(0.f, 0.f, 0.f, 0.f);

    double lsum = 0.0;

    for (int s = 0; s < NCB; ++s) {
        const float* cbs = cb + (size_t)s * KC * DIM;
        const size_t sbase = (size_t)s * NKT * KC * 32;
        const int    coff  = (w * 32 + li) * 32 + lg * 8;   // +jc*512 per cand-tile

        // ---- split phase: rs = fl(x - rec) (bit-exact np), hi/lo bf16 -> LDS ----
        __syncthreads();          // prior stage's readers done
        #pragma unroll
        for (int i = 0; i < 12; ++i) {
            int L = i * THREADS + t;
            int r = L / 96, c4 = L % 96;
            float4 xv = x4[L];
            float4 rs;
            rs.x = xv.x - rec[i].x; rs.y = xv.y - rec[i].y;
            rs.z = xv.z - rec[i].z; rs.w = xv.w - rec[i].w;
            ushort4 h4, l4;
            cvt4(rs, h4, l4);
            *(ushort4*)&ahi[r][c4 * 4] = h4;
            *(ushort4*)&alo[r][c4 * 4] = l4;
        }
        __syncthreads();

        // ---- MFMA screen (no cvt): acc[rt][jc] = rows rt*16.. x cands (2w+jc)*16.. ----
        f32x4 acc[4][2];
        #pragma unroll
        for (int a = 0; a < 4; ++a)
            #pragma unroll
            for (int b = 0; b < 2; ++b) acc[a][b] = (f32x4){0.f, 0.f, 0.f, 0.f};

        bf16x8 bhv[2][2], blv[2][2];
        #pragma unroll
        for (int jc = 0; jc < 2; ++jc) {
            size_t off = sbase + (size_t)(coff + jc * 512);
            bhv[0][jc] = *(const bf16x8*)(cbh_g + off);
            blv[0][jc] = *(const bf16x8*)(cbl_g + off);
        }
        #pragma unroll
        for (int kt = 0; kt < NKT; ++kt) {
            const int cur = kt & 1, nxt = cur ^ 1;
            if (kt + 1 < NKT) {
                #pragma unroll
                for (int jc = 0; jc < 2; ++jc) {
                    size_t off = sbase + (size_t)(kt + 1) * (KC * 32)
                               + (size_t)(coff + jc * 512);
                    bhv[nxt][jc] = *(const bf16x8*)(cbh_g + off);
                    blv[nxt][jc] = *(const bf16x8*)(cbl_g + off);
                }
            }
            #pragma unroll
            for (int rt = 0; rt < 4; ++rt) {
                bf16x8 ah = *(const bf16x8*)&ahi[rt * 16 + li][kt * 32 + lg * 8];
                bf16x8 al = *(const bf16x8*)&alo[rt * 16 + li][kt * 32 + lg * 8];
                #pragma unroll
                for (int jc = 0; jc < 2; ++jc) {
                    acc[rt][jc] = __builtin_amdgcn_mfma_f32_16x16x32_bf16(ah, bhv[cur][jc], acc[rt][jc], 0, 0, 0);
                    acc[rt][jc] = __builtin_amdgcn_mfma_f32_16x16x32_bf16(ah, blv[cur][jc], acc[rt][jc], 0, 0, 0);
                    acc[rt][jc] = __builtin_amdgcn_mfma_f32_16x16x32_bf16(al, bhv[cur][jc], acc[rt][jc], 0, 0, 0);
                }
            }
        }

        // C/D frag: acc[rt][jc][q] = dot(row = rt*16 + lg*4 + q, cand = (2w+jc)*16 + li)
        float ccl2[2];
        #pragma unroll
        for (int jc = 0; jc < 2; ++jc) ccl2[jc] = bpw[s * KC + w * 32 + jc * 16 + li];

        // ---- phase A: per-lane best over jc; butterfly over li; to LDS per wave ----
        float pbv[4][4]; int pbk[4][4];
        #pragma unroll
        for (int rt = 0; rt < 4; ++rt)
            #pragma unroll
            for (int q = 0; q < 4; ++q) {
                float bv = 3.4e38f; int bk = 1 << 30;
                #pragma unroll
                for (int jc = 0; jc < 2; ++jc) {
                    float sv = ccl2[jc] - 2.0f * acc[rt][jc][q];
                    int k = w * 32 + jc * 16 + li;
                    if (sv < bv || (sv == bv && k < bk)) { bv = sv; bk = k; }
                }
                pbv[rt][q] = bv; pbk[rt][q] = bk;
            }
        #pragma unroll
        for (int m = 1; m < 16; m <<= 1) {
            #pragma unroll
            for (int rt = 0; rt < 4; ++rt)
                #pragma unroll
                for (int q = 0; q < 4; ++q) {
                    float ov = __shfl_xor(pbv[rt][q], m);
                    int   ok = __shfl_xor(pbk[rt][q], m);
                    if (ov < pbv[rt][q] || (ov == pbv[rt][q] && ok < pbk[rt][q])) {
                        pbv[rt][q] = ov; pbk[rt][q] = ok;
                    }
                }
        }
        #pragma unroll
        for (int rt = 0; rt < 4; ++rt)
            #pragma unroll
            for (int q = 0; q < 4; ++q)
                if (li == rt * 4 + q) {
                    lvA[rt * 16 + lg * 4 + q][w] = pbv[rt][q];
                    lkA[rt * 16 + lg * 4 + q][w] = pbk[rt][q];
                }
        __syncthreads();

        // ---- row combine across 8 waves (t<64 serial, np tie-break) ----
        if (t < ROWS) {
            float bv = lvA[t][0]; int bk = lkA[t][0];
            #pragma unroll
            for (int ww = 1; ww < NW; ++ww) {
                float v = lvA[t][ww]; int k = lkA[t][ww];
                if (v < bv || (v == bv && k < bk)) { bv = v; bk = k; }
            }
            rowbv[t] = bv; rowbk[t] = bk;
        }
        __syncthreads();

        // ---- margin counts (read rowbv broadcast), butterfly over li ----
        int pcnt[4][4];
        #pragma unroll
        for (int rt = 0; rt < 4; ++rt)
            #pragma unroll
            for (int q = 0; q < 4; ++q) {
                int row = rt * 16 + lg * 4 + q;
                float thr = rowbv[row] + MARGIN;
                int c = 0;
                #pragma unroll
                for (int jc = 0; jc < 2; ++jc) {
                    float sv = ccl2[jc] - 2.0f * acc[rt][jc][q];
                    c += (sv <= thr) ? 1 : 0;
                }
                pcnt[rt][q] = c;
            }
        #pragma unroll
        for (int m = 1; m < 16; m <<= 1) {
            #pragma unroll
            for (int rt = 0; rt < 4; ++rt)
                #pragma unroll
                for (int q = 0; q < 4; ++q)
                    pcnt[rt][q] += __shfl_xor(pcnt[rt][q], m);
        }
        #pragma unroll
        for (int rt = 0; rt < 4; ++rt)
            #pragma unroll
            for (int q = 0; q < 4; ++q)
                if (li == rt * 4 + q) cntA[rt * 16 + lg * 4 + q][w] = pcnt[rt][q];
        __syncthreads();

        // ---- t<64 (wave 0): total counts, unique codes, refine list via ballot ----
        if (t < ROWS) {
            int c = 0;
            #pragma unroll
            for (int ww = 0; ww < NW; ++ww) c += cntA[t][ww];
            bool need = (c >= 2);
            if (!need) codes_s[t][s] = rowbk[t] & 0xFF;
            unsigned long long m = __ballot(need);
            int slot = __popcll(m & ((1ull << t) - 1ull));
            rowslot[t] = need ? slot : -1;
            if (t == 0) nref_s = (int)__popcll(m);
        }
        __syncthreads();
        const int nref = nref_s;

        // ---- refine batches: stage exact rs rows to buf, exact np-f32 refine ----
        for (int base = 0; base < nref; base += NBUF) {
            #pragma unroll
            for (int i = 0; i < 12; ++i) {          // owners stage rs of batch rows
                int L = i * THREADS + t;
                int r = L / 96, c4 = L % 96;
                int sl = rowslot[r];
                if (sl >= base && sl < base + NBUF) {
                    float4 xv = x4[L];
                    float4 rs;
                    rs.x = xv.x - rec[i].x; rs.y = xv.y - rec[i].y;
                    rs.z = xv.z - rec[i].z; rs.w = xv.w - rec[i].w;
                    *(float4*)&buf[sl - base][c4 * 4] = rs;
                }
            }
            __syncthreads();

            #pragma unroll
            for (int rt = 0; rt < 4; ++rt)
                #pragma unroll
                for (int q = 0; q < 4; ++q) {
                    float bd = 3.4e38f; int bk = 1 << 30;
                    int row = rt * 16 + lg * 4 + q;
                    int sl = rowslot[row];
                    if (sl >= base && sl < base + NBUF) {
                        const float* rr = &buf[sl - base][0];
                        float A;
                        {
#pragma clang fp contract(off)
                            float P0 = pw96_sq(rr), P1 = pw96_sq(rr + 96);
                            float P2 = pw96_sq(rr + 192), P3 = pw96_sq(rr + 288);
                            A = (P0 + P1) + (P2 + P3);
                        }
                        const float thr = rowbv[row] + MARGIN;
                        #pragma unroll
                        for (int jc = 0; jc < 2; ++jc) {
                            float sv = ccl2[jc] - 2.0f * acc[rt][jc][q];
                            if (sv <= thr) {
                                int k = w * 32 + jc * 16 + li;
                                const float* crow = cbs + (size_t)k * DIM;
                                float a32 = 0.0f;
                                for (int d = 0; d < DIM; ++d)
                                    a32 = fmaf(rr[d], crow[d], a32);
                                float T  = A + ccl2[jc];     // fl(A + B_k)
                                float dv = T - 2.0f * a32;   // fl(T - 2M), 2M exact
                                if (dv < bd || (dv == bd && k < bk)) { bd = dv; bk = k; }
                            }
                        }
                    }
                    pbv[rt][q] = bd; pbk[rt][q] = bk;
                }
            #pragma unroll
            for (int m = 1; m < 16; m <<= 1) {
                #pragma unroll
                for (int rt = 0; rt < 4; ++rt)
                    #pragma unroll
                    for (int q = 0; q < 4; ++q) {
                        float ov = __shfl_xor(pbv[rt][q], m);
                        int   ok = __shfl_xor(pbk[rt][q], m);
                        if (ov < pbv[rt][q] || (ov == pbv[rt][q] && ok < pbk[rt][q])) {
                            pbv[rt][q] = ov; pbk[rt][q] = ok;
                        }
                    }
            }
            #pragma unroll
            for (int rt = 0; rt < 4; ++rt)
                #pragma unroll
                for (int q = 0; q < 4; ++q)
                    if (li == rt * 4 + q) {
                        lvA[rt * 16 + lg * 4 + q][w] = pbv[rt][q];
                        lkA[rt * 16 + lg * 4 + q][w] = pbk[rt][q];
                    }
            __syncthreads();
            if (t < ROWS) {
                int sl = rowslot[t];
                if (sl >= base && sl < base + NBUF) {
                    float bv = lvA[t][0]; int bk = lkA[t][0];
                    #pragma unroll
                    for (int ww = 1; ww < NW; ++ww) {
                        float v = lvA[t][ww]; int k = lkA[t][ww];
                        if (v < bv || (v == bv && k < bk)) { bv = v; bk = k; }
                    }
                    codes_s[t][s] = bk & 0xFF;
                }
            }
            __syncthreads();      // buf/codes safe; also covers next-batch staging
        }

        // ---- incremental chain: rs recomputed from x (L2) + rec registers ----
        #pragma unroll
        for (int i = 0; i < 12; ++i) {
            int L = i * THREADS + t;
            int r = L / 96, c4 = L % 96;
            int code = codes_s[r][s] & 0xFF;
            float4 q  = ((const float4*)(cbs + (size_t)code * DIM))[c4];
            float4 xv = x4[L];
            float4 rs;                        // fl(x - rec), identical to split phase
            rs.x = xv.x - rec[i].x; rs.y = xv.y - rec[i].y;
            rs.z = xv.z - rec[i].z; rs.w = xv.w - rec[i].w;
            float4 df;
            df.x = q.x - rs.x; df.y = q.y - rs.y;
            df.z = q.z - rs.z; df.w = q.w - rs.w;
            float4 qst;                       // fl(r + fl(q - r))
            qst.x = rs.x + df.x; qst.y = rs.y + df.y;
            qst.z = rs.z + df.z; qst.w = rs.w + df.w;
            rec[i].x = rec[i].x + qst.x; rec[i].y = rec[i].y + qst.y;
            rec[i].z = rec[i].z + qst.z; rec[i].w = rec[i].w + qst.w;
            lsum = fma((double)df.x, (double)df.x, lsum);
            lsum = fma((double)df.y, (double)df.y, lsum);
            lsum = fma((double)df.z, (double)df.z, lsum);
            lsum = fma((double)df.w, (double)df.w, lsum);
        }
    }

    // ---- reconstructed: write rec regs as f32 into out[0 .. B*D) ----
    #pragma unroll
    for (int i = 0; i < 12; ++i) {
        int L = i * THREADS + t;
        ((float4*)out)[(size_t)blockIdx.x * (ROWS * 96) + L] = rec[i];
    }

    // ---- codes as f32 values into out[B*D .. B*D + B*4) ----
    if (t < ROWS) {
        float4 c;
        c.x = (float)(codes_s[t][0] & 0xFF);
        c.y = (float)(codes_s[t][1] & 0xFF);
        c.z = (float)(codes_s[t][2] & 0xFF);
        c.w = (float)(codes_s[t][3] & 0xFF);
        *(float4*)&out[(size_t)BATCH * DIM + (size_t)(row0 + t) * NCB] = c;
    }

    // ---- per-block loss partial ----
    red[t] = lsum;
    __syncthreads();
    for (int st = 256; st > 0; st >>= 1) {
        if (t < st) red[t] += red[t + st];
        __syncthreads();
    }
    if (t == 0) loss_part[blockIdx.x] = red[0];
}

__global__ __launch_bounds__(256) void loss_fin(const double* __restrict__ loss_part,
                                                float* __restrict__ out) {
    __shared__ double red[256];
    int t = threadIdx.x;
    double s = 0.0;
    for (int i = t; i < BATCH / ROWS; i += 256) s += loss_part[i];
    red[t] = s;
    __syncthreads();
    for (int st = 128; st > 0; st >>= 1) {
        if (t < st) red[t] += red[t + st];
        __syncthreads();
    }
    if (t == 0) {
        double total = red[0] * (2.0 / ((double)BATCH * (double)DIM));
        out[(size_t)BATCH * DIM + (size_t)BATCH * NCB] = (float)total;
    }
}

extern "C" void kernel_launch(void* const* d_in, const int* in_sizes, int n_in,
                              void* d_out, int out_size, void* d_ws, size_t ws_size,
                              hipStream_t stream) {
    const float* x  = (const float*)d_in[0];
    const float* cb = (const float*)d_in[1];
    float* out = (float*)d_out;

    double* loss_part = (double*)d_ws;                        // 16 KB @ 0
    float*  bpw       = (float*)((char*)d_ws + 16384);        //  4 KB
    short*  cbh_g     = (short*)((char*)d_ws + 32768);        // 768 KB
    short*  cbl_g     = (short*)((char*)d_ws + 32768 + 786432);

    ccb_kernel<<<dim3(4), dim3(256), 0, stream>>>(cb, bpw);
    split_kernel<<<dim3((NCB * NKT * KC * 32 + 255) / 256), dim3(256), 0, stream>>>(cb, cbh_g, cbl_g);
    rq_main<<<dim3(BATCH / ROWS), dim3(THREADS), 0, stream>>>(x, cb, out, bpw,
                                                              cbh_g, cbl_g, loss_part);
    loss_fin<<<dim3(1), dim3(256), 0, stream>>>(loss_part, out);
}

// Round 14
// 1586.030 us; speedup vs baseline: 1.3392x; 1.3392x over previous
//
#include <hip/hip_runtime.h>
#include <hip/hip_bf16.h>

#define BATCH   131072
#define DIM     384
#define KC      256
#define NCB     4
#define ROWS    64
#define THREADS 512
#define RES_LD  388   // padded row stride (floats) for residual tile
#define NKT     12    // k-tiles of 32 (384 = 12*32)
#define NW      8     // waves per block
#define MARGIN  2.5e-4f

typedef __attribute__((ext_vector_type(8))) short bf16x8;
typedef __attribute__((ext_vector_type(4))) float f32x4;

// numpy pairwise_sum, n=96 block of squares, 8 accumulators (order-preserving).
__device__ __forceinline__ float pw96_sq(const float* a) {
#pragma clang fp contract(off)
    float r0 = a[0]*a[0], r1 = a[1]*a[1], r2 = a[2]*a[2], r3 = a[3]*a[3];
    float r4 = a[4]*a[4], r5 = a[5]*a[5], r6 = a[6]*a[6], r7 = a[7]*a[7];
    for (int i = 8; i < 96; i += 8) {
        r0 += a[i+0]*a[i+0]; r1 += a[i+1]*a[i+1];
        r2 += a[i+2]*a[i+2]; r3 += a[i+3]*a[i+3];
        r4 += a[i+4]*a[i+4]; r5 += a[i+5]*a[i+5];
        r6 += a[i+6]*a[i+6]; r7 += a[i+7]*a[i+7];
    }
    return ((r0+r1)+(r2+r3))+((r4+r5)+(r6+r7));
}

// B_k = numpy pairwise sum of cb_k^2 over 384: ((P0+P1)+(P2+P3))
__global__ __launch_bounds__(256) void ccb_kernel(const float* __restrict__ cb,
                                                  float* __restrict__ bpw) {
    int i = blockIdx.x * 256 + threadIdx.x;
    if (i >= NCB * KC) return;
    const float* row = cb + (size_t)i * DIM;
    {
#pragma clang fp contract(off)
        float P0 = pw96_sq(row), P1 = pw96_sq(row + 96);
        float P2 = pw96_sq(row + 192), P3 = pw96_sq(row + 288);
        bpw[i] = (P0 + P1) + (P2 + P3);
    }
}

// Split codebook into k-tile-major bf16 hi/lo: out[((s*NKT+kt)*KC+cand)*32 + k]
__global__ __launch_bounds__(256) void split_kernel(const float* __restrict__ cb,
                                                    short* __restrict__ hi,
                                                    short* __restrict__ lo) {
    int idx = blockIdx.x * 256 + threadIdx.x;   // over 4*12*256*32 = 393216 elems
    if (idx >= NCB * NKT * KC * 32) return;
    int k    = idx & 31;
    int cand = (idx >> 5) & 255;
    int kt   = (idx >> 13) % NKT;
    int s    = idx / (NKT * KC * 32);
    float v = cb[((size_t)(s * KC + cand)) * DIM + kt * 32 + k];
    __hip_bfloat16 h = __float2bfloat16(v);
    float hv = __bfloat162float(h);
    __hip_bfloat16 l = __float2bfloat16(v - hv);
    hi[idx] = *reinterpret_cast<short*>(&h);
    lo[idx] = *reinterpret_cast<short*>(&l);
}

__device__ __forceinline__ void cvt8(const float* p, bf16x8& hi, bf16x8& lo) {
    #pragma unroll
    for (int i = 0; i < 8; ++i) {
        float v = p[i];
        __hip_bfloat16 h = __float2bfloat16(v);
        float hv = __bfloat162float(h);
        __hip_bfloat16 l = __float2bfloat16(v - hv);
        hi[i] = *reinterpret_cast<short*>(&h);
        lo[i] = *reinterpret_cast<short*>(&l);
    }
}

__global__ __launch_bounds__(512) void rq_main(const float* __restrict__ x,
                                               const float* __restrict__ cb,
                                               float* __restrict__ out,
                                               const float* __restrict__ bpw,
                                               const short* __restrict__ cbh_g,
                                               const short* __restrict__ cbl_g,
                                               double* __restrict__ loss_part) {
    __shared__ float  res[ROWS][RES_LD];      // 99328 B
    __shared__ float  rowbv[ROWS];            //   256 B
    __shared__ int    rowbk[ROWS];            //   256 B
    __shared__ int    rowcnt[ROWS];           //   256 B
    __shared__ float  lvA[ROWS][NW];          //  2048 B
    __shared__ int    lkA[ROWS][NW];          //  2048 B
    __shared__ int    cntA[ROWS][NW];         //  2048 B
    __shared__ int    codes_s[ROWS][NCB];     //  1024 B
    __shared__ double red[THREADS];           //  4096 B   => 111360 B

    const int t  = threadIdx.x;
    const int w  = t >> 6;        // wave 0..7 (owns cand-tiles 2w, 2w+1)
    const int l  = t & 63;
    const int lg = l >> 4;        // k-group 0..3
    const int li = l & 15;
    const int row0 = blockIdx.x * ROWS;
    const float4* x4 = (const float4*)(x + (size_t)row0 * DIM);

    float4 rec[12];               // running reconstruction, this thread's 12 float4s
    #pragma unroll
    for (int i = 0; i < 12; ++i) rec[i] = make_float4(0.f, 0.f, 0.f, 0.f);

    double lsum = 0.0;

    for (int s = 0; s < NCB; ++s) {
        const float* cbs = cb + (size_t)s * KC * DIM;

        // ---- res_s = fl(x - rec) (bit-exact np; s=0: x-0 = x), write to LDS ----
        __syncthreads();          // prior stage's res readers (refine+chain) done
        #pragma unroll
        for (int i = 0; i < 12; ++i) {
            int L = i * THREADS + t;
            int r = L / 96, c4 = L % 96;
            float4 xv = x4[L];
            float4 rs;
            rs.x = xv.x - rec[i].x; rs.y = xv.y - rec[i].y;
            rs.z = xv.z - rec[i].z; rs.w = xv.w - rec[i].w;
            *(float4*)&res[r][c4 * 4] = rs;
        }
        __syncthreads();

        // ---- dual-bf16 MFMA screen: acc[rt][jc] = rows rt*16.. x cands (2w+jc)*16.. ----
        // B fragments straight from global (L2-resident), 2-deep pipelined;
        // kt loop is barrier-free (res is read-only during it).
        f32x4 acc[4][2];
        #pragma unroll
        for (int a = 0; a < 4; ++a)
            #pragma unroll
            for (int b = 0; b < 2; ++b) acc[a][b] = (f32x4){0.f, 0.f, 0.f, 0.f};

        const size_t sbase = (size_t)s * NKT * KC * 32;
        const int    coff  = (w * 32 + li) * 32 + lg * 8;   // +jc*512 per cand-tile

        bf16x8 bhv[2][2], blv[2][2];
        #pragma unroll
        for (int jc = 0; jc < 2; ++jc) {
            size_t off = sbase + (size_t)(coff + jc * 512);
            bhv[0][jc] = *(const bf16x8*)(cbh_g + off);
            blv[0][jc] = *(const bf16x8*)(cbl_g + off);
        }
        #pragma unroll
        for (int kt = 0; kt < NKT; ++kt) {
            const int cur = kt & 1, nxt = cur ^ 1;
            if (kt + 1 < NKT) {
                #pragma unroll
                for (int jc = 0; jc < 2; ++jc) {
                    size_t off = sbase + (size_t)(kt + 1) * (KC * 32)
                               + (size_t)(coff + jc * 512);
                    bhv[nxt][jc] = *(const bf16x8*)(cbh_g + off);
                    blv[nxt][jc] = *(const bf16x8*)(cbl_g + off);
                }
            }
            #pragma unroll
            for (int rt = 0; rt < 4; ++rt) {
                bf16x8 ah, al;
                cvt8(&res[rt * 16 + li][kt * 32 + lg * 8], ah, al);
                #pragma unroll
                for (int jc = 0; jc < 2; ++jc) {
                    acc[rt][jc] = __builtin_amdgcn_mfma_f32_16x16x32_bf16(ah, bhv[cur][jc], acc[rt][jc], 0, 0, 0);
                    acc[rt][jc] = __builtin_amdgcn_mfma_f32_16x16x32_bf16(ah, blv[cur][jc], acc[rt][jc], 0, 0, 0);
                    acc[rt][jc] = __builtin_amdgcn_mfma_f32_16x16x32_bf16(al, bhv[cur][jc], acc[rt][jc], 0, 0, 0);
                }
            }
        }

        // C/D frag: acc[rt][jc][q] = dot(row = rt*16 + lg*4 + q, cand = (2w+jc)*16 + li)
        float ccl2[2];
        #pragma unroll
        for (int jc = 0; jc < 2; ++jc) ccl2[jc] = bpw[s * KC + w * 32 + jc * 16 + li];

        // ---- phase A: per-lane best over jc; butterfly over li; to LDS per wave ----
        float pbv[4][4]; int pbk[4][4];
        #pragma unroll
        for (int rt = 0; rt < 4; ++rt)
            #pragma unroll
            for (int q = 0; q < 4; ++q) {
                float bv = 3.4e38f; int bk = 1 << 30;
                #pragma unroll
                for (int jc = 0; jc < 2; ++jc) {
                    float sv = ccl2[jc] - 2.0f * acc[rt][jc][q];
                    int k = w * 32 + jc * 16 + li;
                    if (sv < bv || (sv == bv && k < bk)) { bv = sv; bk = k; }
                }
                pbv[rt][q] = bv; pbk[rt][q] = bk;
            }
        #pragma unroll
        for (int m = 1; m < 16; m <<= 1) {
            #pragma unroll
            for (int rt = 0; rt < 4; ++rt)
                #pragma unroll
                for (int q = 0; q < 4; ++q) {
                    float ov = __shfl_xor(pbv[rt][q], m);
                    int   ok = __shfl_xor(pbk[rt][q], m);
                    if (ov < pbv[rt][q] || (ov == pbv[rt][q] && ok < pbk[rt][q])) {
                        pbv[rt][q] = ov; pbk[rt][q] = ok;
                    }
                }
        }
        #pragma unroll
        for (int rt = 0; rt < 4; ++rt)
            #pragma unroll
            for (int q = 0; q < 4; ++q)
                if (li == rt * 4 + q) {
                    lvA[rt * 16 + lg * 4 + q][w] = pbv[rt][q];
                    lkA[rt * 16 + lg * 4 + q][w] = pbk[rt][q];
                }
        __syncthreads();

        // ---- row combine across 8 waves (t<64 serial, np tie-break) ----
        if (t < ROWS) {
            float bv = lvA[t][0]; int bk = lkA[t][0];
            #pragma unroll
            for (int ww = 1; ww < NW; ++ww) {
                float v = lvA[t][ww]; int k = lkA[t][ww];
                if (v < bv || (v == bv && k < bk)) { bv = v; bk = k; }
            }
            rowbv[t] = bv; rowbk[t] = bk;
        }
        __syncthreads();

        // ---- margin counts (read rowbv broadcast), butterfly over li ----
        int pcnt[4][4];
        #pragma unroll
        for (int rt = 0; rt < 4; ++rt)
            #pragma unroll
            for (int q = 0; q < 4; ++q) {
                int row = rt * 16 + lg * 4 + q;
                float thr = rowbv[row] + MARGIN;
                int c = 0;
                #pragma unroll
                for (int jc = 0; jc < 2; ++jc) {
                    float sv = ccl2[jc] - 2.0f * acc[rt][jc][q];
                    c += (sv <= thr) ? 1 : 0;
                }
                pcnt[rt][q] = c;
            }
        #pragma unroll
        for (int m = 1; m < 16; m <<= 1) {
            #pragma unroll
            for (int rt = 0; rt < 4; ++rt)
                #pragma unroll
                for (int q = 0; q < 4; ++q)
                    pcnt[rt][q] += __shfl_xor(pcnt[rt][q], m);
        }
        #pragma unroll
        for (int rt = 0; rt < 4; ++rt)
            #pragma unroll
            for (int q = 0; q < 4; ++q)
                if (li == rt * 4 + q) cntA[rt * 16 + lg * 4 + q][w] = pcnt[rt][q];
        __syncthreads();
        if (t < ROWS) {
            int c = 0;
            #pragma unroll
            for (int ww = 0; ww < NW; ++ww) c += cntA[t][ww];
            rowcnt[t] = c;
            if (c == 1) codes_s[t][s] = rowbk[t] & 0xFF;
        }
        __syncthreads();

        // ---- phase C: exact np-f32 refine for rows with >=2 margin candidates ----
        // A = numpy-pairwise sum of res^2 computed on demand (bit-exact np order)
        #pragma unroll
        for (int rt = 0; rt < 4; ++rt)
            #pragma unroll
            for (int q = 0; q < 4; ++q) {
                float bd = 3.4e38f; int bk = 1 << 30;
                int row = rt * 16 + lg * 4 + q;
                if (rowcnt[row] >= 2) {
                    const float thr = rowbv[row] + MARGIN;
                    const float* rrow = &res[row][0];
                    float A;
                    {
#pragma clang fp contract(off)
                        float P0 = pw96_sq(rrow), P1 = pw96_sq(rrow + 96);
                        float P2 = pw96_sq(rrow + 192), P3 = pw96_sq(rrow + 288);
                        A = (P0 + P1) + (P2 + P3);
                    }
                    #pragma unroll
                    for (int jc = 0; jc < 2; ++jc) {
                        float sv = ccl2[jc] - 2.0f * acc[rt][jc][q];
                        if (sv <= thr) {
                            int k = w * 32 + jc * 16 + li;
                            const float* crow = cbs + (size_t)k * DIM;
                            float a32 = 0.0f;
                            for (int d = 0; d < DIM; ++d)
                                a32 = fmaf(rrow[d], crow[d], a32);
                            float T  = A + ccl2[jc];           // fl(A + B_k)
                            float dv = T - 2.0f * a32;         // fl(T - 2M), 2M exact
                            if (dv < bd || (dv == bd && k < bk)) { bd = dv; bk = k; }
                        }
                    }
                }
                pbv[rt][q] = bd; pbk[rt][q] = bk;
            }
        #pragma unroll
        for (int m = 1; m < 16; m <<= 1) {
            #pragma unroll
            for (int rt = 0; rt < 4; ++rt)
                #pragma unroll
                for (int q = 0; q < 4; ++q) {
                    float ov = __shfl_xor(pbv[rt][q], m);
                    int   ok = __shfl_xor(pbk[rt][q], m);
                    if (ov < pbv[rt][q] || (ov == pbv[rt][q] && ok < pbk[rt][q])) {
                        pbv[rt][q] = ov; pbk[rt][q] = ok;
                    }
                }
        }
        #pragma unroll
        for (int rt = 0; rt < 4; ++rt)
            #pragma unroll
            for (int q = 0; q < 4; ++q)
                if (li == rt * 4 + q) {
                    lvA[rt * 16 + lg * 4 + q][w] = pbv[rt][q];
                    lkA[rt * 16 + lg * 4 + q][w] = pbk[rt][q];
                }
        __syncthreads();
        if (t < ROWS && rowcnt[t] >= 2) {
            float bv = lvA[t][0]; int bk = lkA[t][0];
            #pragma unroll
            for (int ww = 1; ww < NW; ++ww) {
                float v = lvA[t][ww]; int k = lkA[t][ww];
                if (v < bv || (v == bv && k < bk)) { bv = v; bk = k; }
            }
            codes_s[t][s] = bk & 0xFF;
        }
        __syncthreads();          // codes_s ready for chain

        // ---- incremental chain: df = q - res; qst = res + df; rec += qst ----
        #pragma unroll
        for (int i = 0; i < 12; ++i) {
            int L = i * THREADS + t;
            int r = L / 96, c4 = L % 96;
            int code = codes_s[r][s] & 0xFF;
            float4 q  = ((const float4*)(cbs + (size_t)code * DIM))[c4];
            float4 rs = *(const float4*)&res[r][c4 * 4];
            float4 df;
            df.x = q.x - rs.x; df.y = q.y - rs.y;
            df.z = q.z - rs.z; df.w = q.w - rs.w;
            float4 qst;                       // fl(r + fl(q - r))
            qst.x = rs.x + df.x; qst.y = rs.y + df.y;
            qst.z = rs.z + df.z; qst.w = rs.w + df.w;
            rec[i].x = rec[i].x + qst.x; rec[i].y = rec[i].y + qst.y;
            rec[i].z = rec[i].z + qst.z; rec[i].w = rec[i].w + qst.w;
            lsum = fma((double)df.x, (double)df.x, lsum);
            lsum = fma((double)df.y, (double)df.y, lsum);
            lsum = fma((double)df.z, (double)df.z, lsum);
            lsum = fma((double)df.w, (double)df.w, lsum);
        }
    }

    // ---- reconstructed: write rec regs as f32 into out[0 .. B*D) ----
    #pragma unroll
    for (int i = 0; i < 12; ++i) {
        int L = i * THREADS + t;
        ((float4*)out)[(size_t)blockIdx.x * (ROWS * 96) + L] = rec[i];
    }

    // ---- codes as f32 values into out[B*D .. B*D + B*4) ----
    if (t < ROWS) {
        float4 c;
        c.x = (float)(codes_s[t][0] & 0xFF);
        c.y = (float)(codes_s[t][1] & 0xFF);
        c.z = (float)(codes_s[t][2] & 0xFF);
        c.w = (float)(codes_s[t][3] & 0xFF);
        *(float4*)&out[(size_t)BATCH * DIM + (size_t)(row0 + t) * NCB] = c;
    }

    // ---- per-block loss partial ----
    red[t] = lsum;
    __syncthreads();
    for (int st = 256; st > 0; st >>= 1) {
        if (t < st) red[t] += red[t + st];
        __syncthreads();
    }
    if (t == 0) loss_part[blockIdx.x] = red[0];
}

__global__ __launch_bounds__(256) void loss_fin(const double* __restrict__ loss_part,
                                                float* __restrict__ out) {
    __shared__ double red[256];
    int t = threadIdx.x;
    double s = 0.0;
    for (int i = t; i < BATCH / ROWS; i += 256) s += loss_part[i];
    red[t] = s;
    __syncthreads();
    for (int st = 128; st > 0; st >>= 1) {
        if (t < st) red[t] += red[t + st];
        __syncthreads();
    }
    if (t == 0) {
        double total = red[0] * (2.0 / ((double)BATCH * (double)DIM));
        out[(size_t)BATCH * DIM + (size_t)BATCH * NCB] = (float)total;
    }
}

extern "C" void kernel_launch(void* const* d_in, const int* in_sizes, int n_in,
                              void* d_out, int out_size, void* d_ws, size_t ws_size,
                              hipStream_t stream) {
    const float* x  = (const float*)d_in[0];
    const float* cb = (const float*)d_in[1];
    float* out = (float*)d_out;

    double* loss_part = (double*)d_ws;                        // 16 KB @ 0
    float*  bpw       = (float*)((char*)d_ws + 16384);        //  4 KB
    short*  cbh_g     = (short*)((char*)d_ws + 32768);        // 768 KB
    short*  cbl_g     = (short*)((char*)d_ws + 32768 + 786432);

    ccb_kernel<<<dim3(4), dim3(256), 0, stream>>>(cb, bpw);
    split_kernel<<<dim3((NCB * NKT * KC * 32 + 255) / 256), dim3(256), 0, stream>>>(cb, cbh_g, cbl_g);
    rq_main<<<dim3(BATCH / ROWS), dim3(THREADS), 0, stream>>>(x, cb, out, bpw,
                                                              cbh_g, cbl_g, loss_part);
    loss_fin<<<dim3(1), dim3(256), 0, stream>>>(loss_part, out);
}

// Round 15
// 1078.957 us; speedup vs baseline: 1.9686x; 1.4700x over previous
//
#include <hip/hip_runtime.h>
#include <hip/hip_bf16.h>

#define BATCH   131072
#define DIM     384
#define KC      256
#define NCB     4
#define ROWS    64
#define THREADS 512
#define RES_LD  388   // padded row stride (floats) for residual tile
#define NKT     12    // k-tiles of 32 (384 = 12*32)
#define NW      8     // waves per block
#define MARGIN  2.5e-4f

typedef __attribute__((ext_vector_type(8))) short bf16x8;
typedef __attribute__((ext_vector_type(4))) float f32x4;

// numpy pairwise_sum, n=96 block of squares, 8 accumulators (order-preserving).
__device__ __forceinline__ float pw96_sq(const float* a) {
#pragma clang fp contract(off)
    float r0 = a[0]*a[0], r1 = a[1]*a[1], r2 = a[2]*a[2], r3 = a[3]*a[3];
    float r4 = a[4]*a[4], r5 = a[5]*a[5], r6 = a[6]*a[6], r7 = a[7]*a[7];
    for (int i = 8; i < 96; i += 8) {
        r0 += a[i+0]*a[i+0]; r1 += a[i+1]*a[i+1];
        r2 += a[i+2]*a[i+2]; r3 += a[i+3]*a[i+3];
        r4 += a[i+4]*a[i+4]; r5 += a[i+5]*a[i+5];
        r6 += a[i+6]*a[i+6]; r7 += a[i+7]*a[i+7];
    }
    return ((r0+r1)+(r2+r3))+((r4+r5)+(r6+r7));
}

// B_k = numpy pairwise sum of cb_k^2 over 384: ((P0+P1)+(P2+P3))
__global__ __launch_bounds__(256) void ccb_kernel(const float* __restrict__ cb,
                                                  float* __restrict__ bpw) {
    int i = blockIdx.x * 256 + threadIdx.x;
    if (i >= NCB * KC) return;
    const float* row = cb + (size_t)i * DIM;
    {
#pragma clang fp contract(off)
        float P0 = pw96_sq(row), P1 = pw96_sq(row + 96);
        float P2 = pw96_sq(row + 192), P3 = pw96_sq(row + 288);
        bpw[i] = (P0 + P1) + (P2 + P3);
    }
}

// Split codebook into k-tile-major bf16 hi/lo: out[((s*NKT+kt)*KC+cand)*32 + k]
__global__ __launch_bounds__(256) void split_kernel(const float* __restrict__ cb,
                                                    short* __restrict__ hi,
                                                    short* __restrict__ lo) {
    int idx = blockIdx.x * 256 + threadIdx.x;   // over 4*12*256*32 = 393216 elems
    if (idx >= NCB * NKT * KC * 32) return;
    int k    = idx & 31;
    int cand = (idx >> 5) & 255;
    int kt   = (idx >> 13) % NKT;
    int s    = idx / (NKT * KC * 32);
    float v = cb[((size_t)(s * KC + cand)) * DIM + kt * 32 + k];
    __hip_bfloat16 h = __float2bfloat16(v);
    float hv = __bfloat162float(h);
    __hip_bfloat16 l = __float2bfloat16(v - hv);
    hi[idx] = *reinterpret_cast<short*>(&h);
    lo[idx] = *reinterpret_cast<short*>(&l);
}

__device__ __forceinline__ void cvt8(const float* p, bf16x8& hi, bf16x8& lo) {
    #pragma unroll
    for (int i = 0; i < 8; ++i) {
        float v = p[i];
        __hip_bfloat16 h = __float2bfloat16(v);
        float hv = __bfloat162float(h);
        __hip_bfloat16 l = __float2bfloat16(v - hv);
        hi[i] = *reinterpret_cast<short*>(&h);
        lo[i] = *reinterpret_cast<short*>(&l);
    }
}

__global__ __launch_bounds__(512) void rq_main(const float* __restrict__ x,
                                               const float* __restrict__ cb,
                                               float* __restrict__ out,
                                               const float* __restrict__ bpw,
                                               const short* __restrict__ cbh_g,
                                               const short* __restrict__ cbl_g,
                                               double* __restrict__ loss_part) {
    __shared__ float  res[ROWS][RES_LD];      // 99328 B
    __shared__ float  rowP[ROWS][4];          //  1024 B
    __shared__ float  rowA[ROWS];             //   256 B
    __shared__ float  rowbv[ROWS];            //   256 B
    __shared__ int    rowbk[ROWS];            //   256 B
    __shared__ int    rowcnt[ROWS];           //   256 B
    __shared__ float  lvA[ROWS][NW];          //  2048 B
    __shared__ int    lkA[ROWS][NW];          //  2048 B
    __shared__ int    cntA[ROWS][NW];         //  2048 B
    __shared__ int    codes_s[ROWS][NCB];     //  1024 B
    __shared__ double red[THREADS];           //  4096 B   => 112640 B

    const int t  = threadIdx.x;
    const int w  = t >> 6;        // wave 0..7 (owns cand-tiles 2w, 2w+1)
    const int l  = t & 63;
    const int lg = l >> 4;        // k-group 0..3
    const int li = l & 15;
    const int row0 = blockIdx.x * ROWS;
    const float4* x4 = (const float4*)(x + (size_t)row0 * DIM);

    float4 rec[12];               // running reconstruction, this thread's 12 float4s
    #pragma unroll
    for (int i = 0; i < 12; ++i) rec[i] = make_float4(0.f, 0.f, 0.f, 0.f);

    double lsum = 0.0;

    for (int s = 0; s < NCB; ++s) {
        const float* cbs = cb + (size_t)s * KC * DIM;

        // ---- res_s = fl(x - rec) (bit-exact np; s=0: x-0 = x), write to LDS ----
        __syncthreads();          // prior stage's res readers (refine+chain) done
        #pragma unroll
        for (int i = 0; i < 12; ++i) {
            int L = i * THREADS + t;
            int r = L / 96, c4 = L % 96;
            float4 xv = x4[L];
            float4 rs;
            rs.x = xv.x - rec[i].x; rs.y = xv.y - rec[i].y;
            rs.z = xv.z - rec[i].z; rs.w = xv.w - rec[i].w;
            *(float4*)&res[r][c4 * 4] = rs;
        }
        __syncthreads();

        // ---- rowA = numpy-pairwise sum of res^2 (bit-exact np order) ----
        if (t < 256) {
            int r = t >> 2, qi = t & 3;
            rowP[r][qi] = pw96_sq(&res[r][qi * 96]);
        }
        __syncthreads();
        if (t < ROWS) {
#pragma clang fp contract(off)
            rowA[t] = (rowP[t][0] + rowP[t][1]) + (rowP[t][2] + rowP[t][3]);
        }
        // rowA consumed in refine; ordered by the phase-A barrier below

        // ---- dual-bf16 MFMA screen: acc[rt][jc] = rows rt*16.. x cands (2w+jc)*16.. ----
        // B fragments straight from global (L2-resident), 2-deep pipelined;
        // kt loop is barrier-free (res is read-only during it).
        f32x4 acc[4][2];
        #pragma unroll
        for (int a = 0; a < 4; ++a)
            #pragma unroll
            for (int b = 0; b < 2; ++b) acc[a][b] = (f32x4){0.f, 0.f, 0.f, 0.f};

        const size_t sbase = (size_t)s * NKT * KC * 32;
        const int    coff  = (w * 32 + li) * 32 + lg * 8;   // +jc*512 per cand-tile

        bf16x8 bhv[2][2], blv[2][2];
        #pragma unroll
        for (int jc = 0; jc < 2; ++jc) {
            size_t off = sbase + (size_t)(coff + jc * 512);
            bhv[0][jc] = *(const bf16x8*)(cbh_g + off);
            blv[0][jc] = *(const bf16x8*)(cbl_g + off);
        }
        #pragma unroll
        for (int kt = 0; kt < NKT; ++kt) {
            const int cur = kt & 1, nxt = cur ^ 1;
            if (kt + 1 < NKT) {
                #pragma unroll
                for (int jc = 0; jc < 2; ++jc) {
                    size_t off = sbase + (size_t)(kt + 1) * (KC * 32)
                               + (size_t)(coff + jc * 512);
                    bhv[nxt][jc] = *(const bf16x8*)(cbh_g + off);
                    blv[nxt][jc] = *(const bf16x8*)(cbl_g + off);
                }
            }
            #pragma unroll
            for (int rt = 0; rt < 4; ++rt) {
                bf16x8 ah, al;
                cvt8(&res[rt * 16 + li][kt * 32 + lg * 8], ah, al);
                #pragma unroll
                for (int jc = 0; jc < 2; ++jc) {
                    acc[rt][jc] = __builtin_amdgcn_mfma_f32_16x16x32_bf16(ah, bhv[cur][jc], acc[rt][jc], 0, 0, 0);
                    acc[rt][jc] = __builtin_amdgcn_mfma_f32_16x16x32_bf16(ah, blv[cur][jc], acc[rt][jc], 0, 0, 0);
                    acc[rt][jc] = __builtin_amdgcn_mfma_f32_16x16x32_bf16(al, bhv[cur][jc], acc[rt][jc], 0, 0, 0);
                }
            }
        }

        // C/D frag: acc[rt][jc][q] = dot(row = rt*16 + lg*4 + q, cand = (2w+jc)*16 + li)
        float ccl2[2];
        #pragma unroll
        for (int jc = 0; jc < 2; ++jc) ccl2[jc] = bpw[s * KC + w * 32 + jc * 16 + li];

        // ---- phase A: per-lane best over jc; butterfly over li; to LDS per wave ----
        float pbv[4][4]; int pbk[4][4];
        #pragma unroll
        for (int rt = 0; rt < 4; ++rt)
            #pragma unroll
            for (int q = 0; q < 4; ++q) {
                float bv = 3.4e38f; int bk = 1 << 30;
                #pragma unroll
                for (int jc = 0; jc < 2; ++jc) {
                    float sv = ccl2[jc] - 2.0f * acc[rt][jc][q];
                    int k = w * 32 + jc * 16 + li;
                    if (sv < bv || (sv == bv && k < bk)) { bv = sv; bk = k; }
                }
                pbv[rt][q] = bv; pbk[rt][q] = bk;
            }
        #pragma unroll
        for (int m = 1; m < 16; m <<= 1) {
            #pragma unroll
            for (int rt = 0; rt < 4; ++rt)
                #pragma unroll
                for (int q = 0; q < 4; ++q) {
                    float ov = __shfl_xor(pbv[rt][q], m);
                    int   ok = __shfl_xor(pbk[rt][q], m);
                    if (ov < pbv[rt][q] || (ov == pbv[rt][q] && ok < pbk[rt][q])) {
                        pbv[rt][q] = ov; pbk[rt][q] = ok;
                    }
                }
        }
        #pragma unroll
        for (int rt = 0; rt < 4; ++rt)
            #pragma unroll
            for (int q = 0; q < 4; ++q)
                if (li == rt * 4 + q) {
                    lvA[rt * 16 + lg * 4 + q][w] = pbv[rt][q];
                    lkA[rt * 16 + lg * 4 + q][w] = pbk[rt][q];
                }
        __syncthreads();

        // ---- row combine across 8 waves (t<64 serial, np tie-break) ----
        if (t < ROWS) {
            float bv = lvA[t][0]; int bk = lkA[t][0];
            #pragma unroll
            for (int ww = 1; ww < NW; ++ww) {
                float v = lvA[t][ww]; int k = lkA[t][ww];
                if (v < bv || (v == bv && k < bk)) { bv = v; bk = k; }
            }
            rowbv[t] = bv; rowbk[t] = bk;
        }
        __syncthreads();

        // ---- margin counts (read rowbv broadcast), butterfly over li ----
        int pcnt[4][4];
        #pragma unroll
        for (int rt = 0; rt < 4; ++rt)
            #pragma unroll
            for (int q = 0; q < 4; ++q) {
                int row = rt * 16 + lg * 4 + q;
                float thr = rowbv[row] + MARGIN;
                int c = 0;
                #pragma unroll
                for (int jc = 0; jc < 2; ++jc) {
                    float sv = ccl2[jc] - 2.0f * acc[rt][jc][q];
                    c += (sv <= thr) ? 1 : 0;
                }
                pcnt[rt][q] = c;
            }
        #pragma unroll
        for (int m = 1; m < 16; m <<= 1) {
            #pragma unroll
            for (int rt = 0; rt < 4; ++rt)
                #pragma unroll
                for (int q = 0; q < 4; ++q)
                    pcnt[rt][q] += __shfl_xor(pcnt[rt][q], m);
        }
        #pragma unroll
        for (int rt = 0; rt < 4; ++rt)
            #pragma unroll
            for (int q = 0; q < 4; ++q)
                if (li == rt * 4 + q) cntA[rt * 16 + lg * 4 + q][w] = pcnt[rt][q];
        __syncthreads();
        if (t < ROWS) {
            int c = 0;
            #pragma unroll
            for (int ww = 0; ww < NW; ++ww) c += cntA[t][ww];
            rowcnt[t] = c;
            if (c == 1) codes_s[t][s] = rowbk[t] & 0xFF;
        }
        __syncthreads();

        // ---- phase C: exact np-f32 refine for rows with >=2 margin candidates ----
        #pragma unroll
        for (int rt = 0; rt < 4; ++rt)
            #pragma unroll
            for (int q = 0; q < 4; ++q) {
                float bd = 3.4e38f; int bk = 1 << 30;
                int row = rt * 16 + lg * 4 + q;
                if (rowcnt[row] >= 2) {
                    const float thr = rowbv[row] + MARGIN;
                    const float* rrow = &res[row][0];
                    #pragma unroll
                    for (int jc = 0; jc < 2; ++jc) {
                        float sv = ccl2[jc] - 2.0f * acc[rt][jc][q];
                        if (sv <= thr) {
                            int k = w * 32 + jc * 16 + li;
                            const float* crow = cbs + (size_t)k * DIM;
                            float a32 = 0.0f;
                            for (int d = 0; d < DIM; ++d)
                                a32 = fmaf(rrow[d], crow[d], a32);
                            float T  = rowA[row] + ccl2[jc];   // fl(A + B_k)
                            float dv = T - 2.0f * a32;         // fl(T - 2M), 2M exact
                            if (dv < bd || (dv == bd && k < bk)) { bd = dv; bk = k; }
                        }
                    }
                }
                pbv[rt][q] = bd; pbk[rt][q] = bk;
            }
        #pragma unroll
        for (int m = 1; m < 16; m <<= 1) {
            #pragma unroll
            for (int rt = 0; rt < 4; ++rt)
                #pragma unroll
                for (int q = 0; q < 4; ++q) {
                    float ov = __shfl_xor(pbv[rt][q], m);
                    int   ok = __shfl_xor(pbk[rt][q], m);
                    if (ov < pbv[rt][q] || (ov == pbv[rt][q] && ok < pbk[rt][q])) {
                        pbv[rt][q] = ov; pbk[rt][q] = ok;
                    }
                }
        }
        #pragma unroll
        for (int rt = 0; rt < 4; ++rt)
            #pragma unroll
            for (int q = 0; q < 4; ++q)
                if (li == rt * 4 + q) {
                    lvA[rt * 16 + lg * 4 + q][w] = pbv[rt][q];
                    lkA[rt * 16 + lg * 4 + q][w] = pbk[rt][q];
                }
        __syncthreads();
        if (t < ROWS && rowcnt[t] >= 2) {
            float bv = lvA[t][0]; int bk = lkA[t][0];
            #pragma unroll
            for (int ww = 1; ww < NW; ++ww) {
                float v = lvA[t][ww]; int k = lkA[t][ww];
                if (v < bv || (v == bv && k < bk)) { bv = v; bk = k; }
            }
            codes_s[t][s] = bk & 0xFF;
        }
        __syncthreads();          // codes_s ready for chain

        // ---- incremental chain: df = q - res; qst = res + df; rec += qst ----
        #pragma unroll
        for (int i = 0; i < 12; ++i) {
            int L = i * THREADS + t;
            int r = L / 96, c4 = L % 96;
            int code = codes_s[r][s] & 0xFF;
            float4 q  = ((const float4*)(cbs + (size_t)code * DIM))[c4];
            float4 rs = *(const float4*)&res[r][c4 * 4];
            float4 df;
            df.x = q.x - rs.x; df.y = q.y - rs.y;
            df.z = q.z - rs.z; df.w = q.w - rs.w;
            float4 qst;                       // fl(r + fl(q - r))
            qst.x = rs.x + df.x; qst.y = rs.y + df.y;
            qst.z = rs.z + df.z; qst.w = rs.w + df.w;
            rec[i].x = rec[i].x + qst.x; rec[i].y = rec[i].y + qst.y;
            rec[i].z = rec[i].z + qst.z; rec[i].w = rec[i].w + qst.w;
            lsum = fma((double)df.x, (double)df.x, lsum);
            lsum = fma((double)df.y, (double)df.y, lsum);
            lsum = fma((double)df.z, (double)df.z, lsum);
            lsum = fma((double)df.w, (double)df.w, lsum);
        }
    }

    // ---- reconstructed: write rec regs as f32 into out[0 .. B*D) ----
    #pragma unroll
    for (int i = 0; i < 12; ++i) {
        int L = i * THREADS + t;
        ((float4*)out)[(size_t)blockIdx.x * (ROWS * 96) + L] = rec[i];
    }

    // ---- codes as f32 values into out[B*D .. B*D + B*4) ----
    if (t < ROWS) {
        float4 c;
        c.x = (float)(codes_s[t][0] & 0xFF);
        c.y = (float)(codes_s[t][1] & 0xFF);
        c.z = (float)(codes_s[t][2] & 0xFF);
        c.w = (float)(codes_s[t][3] & 0xFF);
        *(float4*)&out[(size_t)BATCH * DIM + (size_t)(row0 + t) * NCB] = c;
    }

    // ---- per-block loss partial ----
    red[t] = lsum;
    __syncthreads();
    for (int st = 256; st > 0; st >>= 1) {
        if (t < st) red[t] += red[t + st];
        __syncthreads();
    }
    if (t == 0) loss_part[blockIdx.x] = red[0];
}

__global__ __launch_bounds__(256) void loss_fin(const double* __restrict__ loss_part,
                                                float* __restrict__ out) {
    __shared__ double red[256];
    int t = threadIdx.x;
    double s = 0.0;
    for (int i = t; i < BATCH / ROWS; i += 256) s += loss_part[i];
    red[t] = s;
    __syncthreads();
    for (int st = 128; st > 0; st >>= 1) {
        if (t < st) red[t] += red[t + st];
        __syncthreads();
    }
    if (t == 0) {
        double total = red[0] * (2.0 / ((double)BATCH * (double)DIM));
        out[(size_t)BATCH * DIM + (size_t)BATCH * NCB] = (float)total;
    }
}

extern "C" void kernel_launch(void* const* d_in, const int* in_sizes, int n_in,
                              void* d_out, int out_size, void* d_ws, size_t ws_size,
                              hipStream_t stream) {
    const float* x  = (const float*)d_in[0];
    const float* cb = (const float*)d_in[1];
    float* out = (float*)d_out;

    double* loss_part = (double*)d_ws;                        // 16 KB @ 0
    float*  bpw       = (float*)((char*)d_ws + 16384);        //  4 KB
    short*  cbh_g     = (short*)((char*)d_ws + 32768);        // 768 KB
    short*  cbl_g     = (short*)((char*)d_ws + 32768 + 786432);

    ccb_kernel<<<dim3(4), dim3(256), 0, stream>>>(cb, bpw);
    split_kernel<<<dim3((NCB * NKT * KC * 32 + 255) / 256), dim3(256), 0, stream>>>(cb, cbh_g, cbl_g);
    rq_main<<<dim3(BATCH / ROWS), dim3(THREADS), 0, stream>>>(x, cb, out, bpw,
                                                              cbh_g, cbl_g, loss_part);
    loss_fin<<<dim3(1), dim3(256), 0, stream>>>(loss_part, out);
}